// Round 19
// baseline (426.781 us; speedup 1.0000x reference)
//
#include <hip/hip_runtime.h>
#include <hip/hip_cooperative_groups.h>
#include <cstddef>

namespace cg = cooperative_groups;

// ---------------------------------------------------------------------------
// SAGEBlock: 3-layer GraphSAGE (mean aggr), N=50000, E=800000.
//   h1 = relu(agg(x)@Wl1 + x@Wr1 + b1)              128 -> 256
//   h2 = relu(agg(h1@Wl2) + h1@Wr2 + b2)            256 -> 128
//   out= sigmoid(agg(h2@Wl3) + h2@Wr3 + b3)         128 -> 64
// R19: R18 (189.6us) + cooperative fused PREP kernel: {memset, pcount, pscan,
//     scatter, build, cvt_all} -> 1 dispatch with grid.sync() phases. The cvt
//     work (independent of CSR) runs on idle blocks DURING the CSR phases;
//     pscan runs on block 0 while 511 blocks convert. Saves ~5 graph-node
//     boundaries + overlaps ~9us of cvt. agg/gemm pipeline unchanged.
// ---------------------------------------------------------------------------

using frag  = __attribute__((ext_vector_type(8))) short;   // 8 bf16
using f32x4 = __attribute__((ext_vector_type(4))) float;
using vf2   = __attribute__((ext_vector_type(2))) float;
typedef unsigned char u8;

constexpr int PBITS = 9;                 // 512 nodes per partition
constexpr int PSZ   = 1 << PBITS;
constexpr int PMAX  = 128;               // max partitions (M <= 65536)

__device__ __forceinline__ ushort f2bf(float f) {
    union { float f; unsigned u; } v; v.f = f;
    unsigned r = v.u + 0x7FFF + ((v.u >> 16) & 1);   // RNE
    return (ushort)(r >> 16);
}
__device__ __forceinline__ float bf2f(ushort u) {
    union { unsigned u; float f; } v; v.u = ((unsigned)u) << 16;
    return v.f;
}

// ---------------- converts descriptor ----------------

struct CvtDesc {
    const float* s[6];
    ushort*      d[6];
    int K[6];    // src K
    int N[6];    // src N
    int KD[6];   // dst row stride
    int KO[6];   // dst k offset
};

// one cvt "unit" = 256 threads worth of convert work
__device__ __forceinline__ void do_cvt_unit(int u, const CvtDesc& c,
                                            const float* __restrict__ x,
                                            ushort* __restrict__ AX,
                                            u8* __restrict__ x8,
                                            int n4, int xunits) {
    int t = threadIdx.x;
    if (u < xunits) {
        int i = u * 256 + t;
        if (i < n4) {
            int row = i >> 5;            // 32 float4 per row of 128
            int c4  = i & 31;
            float4 v = ((const float4*)x)[i];
            ushort4 o; o.x = f2bf(v.x); o.y = f2bf(v.y); o.z = f2bf(v.z); o.w = f2bf(v.w);
            *(ushort4*)(AX + (size_t)row * 256 + 128 + c4 * 4) = o;
            int pk = __builtin_amdgcn_cvt_pk_fp8_f32(v.x, v.y, 0, false);
            pk = __builtin_amdgcn_cvt_pk_fp8_f32(v.z, v.w, pk, true);
            *(int*)(x8 + (size_t)row * 128 + c4 * 4) = pk;
        }
    } else {
        int wb = u - xunits;
        int wi = wb >> 7;
        int tt = (wb & 127) * 256 + t;
        int K = c.K[wi], N = c.N[wi];
        if (tt < K * N) {
            int k = tt / N, n = tt % N;
            c.d[wi][(size_t)n * c.KD[wi] + c.KO[wi] + k] = f2bf(c.s[wi][tt]);
        }
    }
}

// ---------------- cooperative PREP: CSR counting sort + cvt overlap ---------
// Phases (grid.sync between): 0) zero pcount | cvt; 1) pcount | cvt;
// 2) pscan(b0) | cvt; 3) scatter; 4) build.

__global__ __launch_bounds__(256)
void k_prep(const float* __restrict__ x, const int* __restrict__ src,
            const int* __restrict__ dst,
            int* __restrict__ pcount, int* __restrict__ pbase,
            int* __restrict__ pcursor, unsigned* __restrict__ pairs,
            ushort* __restrict__ csr16, int* __restrict__ deg,
            int* __restrict__ row_start,
            CvtDesc cd, ushort* __restrict__ AX, u8* __restrict__ x8,
            int M, int E, int P, int nchunk, int n4, int xunits, int tunits) {
    cg::grid_group grid = cg::this_grid();
    __shared__ int shA[PSZ];     // h / cnt
    __shared__ int shB[PSZ];     // off / ls
    __shared__ int shC[PSZ];     // fil
    __shared__ int shD[256];     // ws
    const int b = blockIdx.x;
    const int t = threadIdx.x;
    const int NB = gridDim.x;    // 512

    // ---- phase 0: zero pcount (block 0); cvt on blocks 1..NB-1 (4 units each)
    if (b == 0) {
        if (t < PMAX) pcount[t] = 0;
    } else {
        int base = (b - 1) * 4;
        #pragma unroll
        for (int q = 0; q < 4; ++q) {
            int u = base + q;
            if (u < tunits) do_cvt_unit(u, cd, x, AX, x8, n4, xunits);
        }
    }
    grid.sync();

    // ---- phase 1: pcount (blocks < nchunk); cvt on the rest (6 units each)
    const int ph1base = (NB - 1) * 4;
    if (b < nchunk) {
        if (t < P) shA[t] = 0;
        __syncthreads();
        int base = b * 4096;
        int n = min(4096, E - base);
        for (int i = t; i < n; i += 256)
            atomicAdd(&shA[dst[base + i] >> PBITS], 1);
        __syncthreads();
        if (t < P && shA[t]) atomicAdd(&pcount[t], shA[t]);
    } else {
        int base = ph1base + (b - nchunk) * 6;
        #pragma unroll
        for (int q = 0; q < 6; ++q) {
            int u = base + q;
            if (u < tunits) do_cvt_unit(u, cd, x, AX, x8, n4, xunits);
        }
    }
    grid.sync();

    // ---- phase 2: pscan (block 0, serial); cvt remainder (7 units each)
    const int ph2base = ph1base + (NB - nchunk) * 6;
    if (b == 0) {
        if (t == 0) {
            int run = 0;
            for (int p = 0; p < P; ++p) {
                pbase[p] = run; pcursor[p] = run; run += pcount[p];
            }
            pbase[P] = run;
        }
    } else {
        int base = ph2base + (b - 1) * 7;
        #pragma unroll
        for (int q = 0; q < 7; ++q) {
            int u = base + q;
            if (u < tunits) do_cvt_unit(u, cd, x, AX, x8, n4, xunits);
        }
    }
    grid.sync();

    // ---- phase 3: scatter (blocks < nchunk)
    if (b < nchunk) {
        if (t < P) shA[t] = 0;
        __syncthreads();
        int base = b * 4096;
        int pp[16]; int pr[16]; unsigned pk[16];
        #pragma unroll
        for (int ii = 0; ii < 16; ++ii) {      // static index -> stays in VGPRs
            int idx = base + ii * 256 + t;
            bool v = idx < E;
            int d = v ? dst[idx] : 0;
            int p = d >> PBITS;
            pp[ii] = v ? p : -1;
            pr[ii] = v ? atomicAdd(&shA[p], 1) : 0;
            pk[ii] = v ? ((unsigned)src[idx] | ((unsigned)(d & (PSZ - 1)) << 16)) : 0u;
        }
        __syncthreads();
        if (t < P && shA[t]) shB[t] = atomicAdd(&pcursor[t], shA[t]);
        __syncthreads();
        #pragma unroll
        for (int ii = 0; ii < 16; ++ii)
            if (pp[ii] >= 0) pairs[shB[pp[ii]] + pr[ii]] = pk[ii];
    }
    grid.sync();

    // ---- phase 4: build (blocks < P)
    if (b < P) {
        int n0 = b << PBITS;
        int L = min(PSZ, M - n0);
        int wb = pbase[b], we = pbase[b + 1];
        int ne = we - wb;
        for (int j = t; j < PSZ; j += 256) { shA[j] = 0; shC[j] = 0; }
        __syncthreads();
        for (int i = t; i < ne; i += 256)
            atomicAdd(&shA[pairs[wb + i] >> 16], 1);
        __syncthreads();
        int a = shA[2 * t], bb = shA[2 * t + 1];
        shD[t] = a + bb;
        __syncthreads();
        for (int o = 1; o < 256; o <<= 1) {
            int v = (t >= o) ? shD[t - o] : 0;
            __syncthreads();
            shD[t] += v;
            __syncthreads();
        }
        int excl = (t > 0) ? shD[t - 1] : 0;
        shB[2 * t] = excl; shB[2 * t + 1] = excl + a;
        __syncthreads();
        for (int j = t; j < L; j += 256) {
            deg[n0 + j] = shA[j];
            row_start[n0 + j] = wb + shB[j];
        }
        for (int i = t; i < ne; i += 256) {
            unsigned pk = pairs[wb + i];
            int ln = pk >> 16;
            int pos = wb + shB[ln] + atomicAdd(&shC[ln], 1);
            csr16[pos] = (ushort)(pk & 0xFFFFu);
        }
    }
}

// ---------------- mean aggregation + fused epilogue ----------------
// F/4 lanes per node. IN8: gather input is fp8 (LDI in BYTES, uint/lane);
// else bf16 (LDI in ushorts, ushort4/lane). LDO: out row stride.
// EPI: 0 = plain bf16 out; 1 = relu(agg+u+b) bf16 out; 2 = sigmoid(agg+u+b) f32 out

template <int F, int EPI, int IN8, int LDI, int LDO>
__global__ __launch_bounds__(256)
void agg_bf(const void* __restrict__ inv, const ushort* __restrict__ csr16,
            const int* __restrict__ row_start, const int* __restrict__ deg,
            const ushort* __restrict__ u, const float* __restrict__ bias,
            void* __restrict__ out, int nN) {
    constexpr int GPL = F / 4;                 // lanes per node
    constexpr int NPB = 256 / GPL;             // nodes per block
    int gid  = threadIdx.x / GPL;
    int li   = threadIdx.x % GPL;
    int node = blockIdx.x * NPB + gid;
    bool valid = node < nN;
    int start = valid ? row_start[node] : 0;
    int d     = valid ? deg[node] : 0;
    float a0 = 0.f, a1 = 0.f, a2 = 0.f, a3 = 0.f;

    auto gat = [&](int j) {
        int s = csr16[start + j];
        if constexpr (IN8) {
            int uu = *(const int*)((const u8*)inv + (size_t)s * LDI + li * 4);
            vf2 lo = __builtin_amdgcn_cvt_pk_f32_fp8(uu, false);
            vf2 hi = __builtin_amdgcn_cvt_pk_f32_fp8(uu, true);
            a0 += lo[0]; a1 += lo[1]; a2 += hi[0]; a3 += hi[1];
        } else {
            ushort4 uv = *(const ushort4*)((const ushort*)inv + (size_t)s * LDI + li * 4);
            a0 += bf2f(uv.x); a1 += bf2f(uv.y); a2 += bf2f(uv.z); a3 += bf2f(uv.w);
        }
    };

    int j = 0;
    for (; j + 8 <= d; j += 8) {
        gat(j); gat(j+1); gat(j+2); gat(j+3);
        gat(j+4); gat(j+5); gat(j+6); gat(j+7);
    }
    for (; j + 2 <= d; j += 2) { gat(j); gat(j+1); }
    for (; j < d; ++j) gat(j);

    if (!valid) return;
    float inv_d = 1.f / (float)(d > 0 ? d : 1);
    a0 *= inv_d; a1 *= inv_d; a2 *= inv_d; a3 *= inv_d;

    size_t o4 = (size_t)node * LDO + li * 4;
    if constexpr (EPI == 0) {
        ushort4 o; o.x = f2bf(a0); o.y = f2bf(a1); o.z = f2bf(a2); o.w = f2bf(a3);
        *(ushort4*)((ushort*)out + o4) = o;
    } else {
        ushort4 uv = *(const ushort4*)(u + (size_t)node * F + li * 4);
        float4 bv = *(const float4*)(bias + li * 4);
        a0 += bf2f(uv.x) + bv.x;
        a1 += bf2f(uv.y) + bv.y;
        a2 += bf2f(uv.z) + bv.z;
        a3 += bf2f(uv.w) + bv.w;
        if constexpr (EPI == 1) {
            ushort4 o;
            o.x = f2bf(fmaxf(a0, 0.f)); o.y = f2bf(fmaxf(a1, 0.f));
            o.z = f2bf(fmaxf(a2, 0.f)); o.w = f2bf(fmaxf(a3, 0.f));
            *(ushort4*)((ushort*)out + o4) = o;
        } else {
            float4 o;
            o.x = 1.f / (1.f + __expf(-a0)); o.y = 1.f / (1.f + __expf(-a1));
            o.z = 1.f / (1.f + __expf(-a2)); o.w = 1.f / (1.f + __expf(-a3));
            *(float4*)((float*)out + o4) = o;
        }
    }
}

// ---------------- bf16 MFMA GEMM: 2-phase pipelined, gload_lds staging ------
// C[M,N] = act( A@B^T (+ bias) ); col < nsplit -> C1, else C2.
// OUT8: C1 stored as fp8 (gather operand); C2 always bf16.
// Double-buffered LDS, ONE barrier per K-step; prefetch overlaps compute.
// Swizzle: linear LDS dest + inverse-XOR global source (rule #21).

__device__ __forceinline__ void gload16(const ushort* gp, char* lp) {
    __builtin_amdgcn_global_load_lds(
        (const __attribute__((address_space(1))) void*)gp,
        (__attribute__((address_space(3))) void*)lp, 16, 0, 0);
}

template <int BM, int BN, int K, int ACT, int OUT8>
__global__ __launch_bounds__(256)
void mgemm(const ushort* __restrict__ A, const ushort* __restrict__ B,
           const float* __restrict__ bias,
           void* __restrict__ C1, int ld1,
           ushort* __restrict__ C2, int ld2, int nsplit,
           int M, int N) {
    constexpr int NW = 4;                     // waves per block
    constexpr int WM = 2, WN = 2;
    constexpr int MF = BM / (WM * 16);
    constexpr int NF = BN / (WN * 16);
    constexpr int NSTEP = K / 64;
    constexpr int TB = (BM + BN) * 128;       // bytes per buffer
    __shared__ char lds[2 * TB];

    const int tid  = threadIdx.x;
    const int lane = tid & 63;
    const int wid  = tid >> 6;
    const int wm   = wid % WM, wn = wid / WM;
    const int bm   = blockIdx.x * BM;
    const int bn   = blockIdx.y * BN;
    const int l15  = lane & 15;
    const int lhi  = lane >> 4;
    const int lr8  = lane >> 3;               // row within 8-row gload group
    const int lf   = lane & 7;                // frag slot within row

    auto stage = [&](int buf, int k0) {
        char* As = lds + buf * TB;
        char* Bs = As + BM * 128;
        #pragma unroll
        for (int it = 0; it < BM / (8 * NW); ++it) {
            int r0 = (it * NW + wid) * 8;
            int row = r0 + lr8;
            int gr = bm + row; if (gr >= M) gr = M - 1;   // clamp; junk rows unused
            int gfc = lf ^ (row & 7);
            gload16(A + (size_t)gr * K + k0 + gfc * 8, As + r0 * 128);
        }
        #pragma unroll
        for (int it = 0; it < BN / (8 * NW); ++it) {
            int r0 = (it * NW + wid) * 8;
            int row = r0 + lr8;
            int gfc = lf ^ (row & 7);
            gload16(B + (size_t)(bn + row) * K + k0 + gfc * 8, Bs + r0 * 128);
        }
    };

    f32x4 acc[MF][NF] = {};

    stage(0, 0);
    #pragma unroll
    for (int s = 0; s < NSTEP; ++s) {
        __syncthreads();                       // drains stage(s)
        if (s + 1 < NSTEP) stage((s + 1) & 1, (s + 1) * 64);   // prefetch overlaps compute
        char* As = lds + (s & 1) * TB;
        char* Bs = As + BM * 128;
        #pragma unroll
        for (int ks = 0; ks < 2; ++ks) {
            const int kb = ks * 64 + lhi * 16;
            frag a[MF], b[NF];
            #pragma unroll
            for (int mf = 0; mf < MF; ++mf) {
                int row = wm * MF * 16 + mf * 16 + l15;
                a[mf] = *(const frag*)(As + row * 128 + (kb ^ ((row & 7) << 4)));
            }
            #pragma unroll
            for (int nf = 0; nf < NF; ++nf) {
                int row = wn * NF * 16 + nf * 16 + l15;
                b[nf] = *(const frag*)(Bs + row * 128 + (kb ^ ((row & 7) << 4)));
            }
            #pragma unroll
            for (int mf = 0; mf < MF; ++mf)
                #pragma unroll
                for (int nf = 0; nf < NF; ++nf)
                    acc[mf][nf] = __builtin_amdgcn_mfma_f32_16x16x32_bf16(
                        a[mf], b[nf], acc[mf][nf], 0, 0, 0);
        }
    }

    #pragma unroll
    for (int mf = 0; mf < MF; ++mf) {
        #pragma unroll
        for (int r = 0; r < 4; ++r) {
            int gm = bm + wm * MF * 16 + mf * 16 + lhi * 4 + r;
            if (gm >= M) continue;
            #pragma unroll
            for (int nf = 0; nf < NF; ++nf) {
                int gn = bn + wn * NF * 16 + nf * 16 + l15;
                float v = acc[mf][nf][r];
                if (bias) v += bias[gn];
                if (ACT == 1) v = fmaxf(v, 0.f);
                if (gn < nsplit) {
                    if constexpr (OUT8) {
                        int pk = __builtin_amdgcn_cvt_pk_fp8_f32(v, v, 0, false);
                        ((u8*)C1)[(size_t)gm * ld1 + gn] = (u8)(pk & 0xFF);
                    } else {
                        ((ushort*)C1)[(size_t)gm * ld1 + gn] = f2bf(v);
                    }
                } else {
                    C2[(size_t)gm * ld2 + (gn - nsplit)] = f2bf(v);
                }
            }
        }
    }
}

// ---------------------------------------------------------------------------

extern "C" void kernel_launch(void* const* d_in, const int* in_sizes, int n_in,
                              void* d_out, int out_size, void* d_ws, size_t ws_size,
                              hipStream_t stream) {
    const float* x   = (const float*)d_in[0];
    const int*   ei  = (const int*)d_in[1];
    const float* Wl1 = (const float*)d_in[2];
    const float* Wr1 = (const float*)d_in[3];
    const float* b1  = (const float*)d_in[4];
    const float* Wl2 = (const float*)d_in[5];
    const float* Wr2 = (const float*)d_in[6];
    const float* b2  = (const float*)d_in[7];
    const float* Wl3 = (const float*)d_in[8];
    const float* Wr3 = (const float*)d_in[9];
    const float* b3  = (const float*)d_in[10];

    const int M = in_sizes[0] / 128;   // 50000
    const int E = in_sizes[1] / 2;     // 800000
    const int P = (M + PSZ - 1) / PSZ; // 98 partitions
    const int* src = ei;
    const int* dst = ei + E;

    char* w = (char*)d_ws;
    auto alloc = [&](size_t bytes) -> void* {
        void* p = (void*)w;
        w += (bytes + 255) & ~(size_t)255;
        return p;
    };
    int* pcount    = (int*)alloc((size_t)PMAX * 4);
    int* pbase     = (int*)alloc((size_t)(PMAX + 1) * 4);
    int* pcursor   = (int*)alloc((size_t)PMAX * 4);
    unsigned* pairs = (unsigned*)alloc((size_t)E * 4);
    ushort* csr16  = (ushort*)alloc((size_t)E * 2);
    int* deg       = (int*)alloc((size_t)M * 4);
    int* row_start = (int*)alloc((size_t)M * 4);
    ushort* Wcat1T = (ushort*)alloc(256 * 256 * 2);       // [256 n][256 k]: Wl1|Wr1 (K-concat)
    ushort* Wcat2T = (ushort*)alloc(256 * 256 * 2);       // [256 n][256 k]: Wl2|Wr2 (N-concat)
    ushort* Wcat3T = (ushort*)alloc(128 * 128 * 2);       // [128 n][128 k]: Wl3|Wr3 (N-concat)
    ushort* AX   = (ushort*)alloc((size_t)M * 256 * 2);   // [aggx | x_bf] interleaved
    ushort* bufB = (ushort*)alloc((size_t)M * 128 * 2);   // h2
    ushort* bufH = (ushort*)alloc((size_t)M * 256 * 2);   // h1
    ushort* bufC = (ushort*)alloc((size_t)M * 128 * 2);   // u2 -> u3
    u8* fp8buf   = (u8*)alloc((size_t)M * 128);           // x8 -> t2_8 -> t3_8 (time-shared)
    (void)ws_size; (void)n_in; (void)out_size;

    ushort* h2 = bufB;
    ushort* h1 = bufH;
    ushort* u2 = bufC;   ushort* u3 = bufC;
    u8* x8   = fp8buf;   u8* t2_8 = fp8buf;   u8* t3_8 = fp8buf;
    // x8 dead before gemm2 writes t2_8; t2_8 dead (agg2 done) before gemm3 writes t3_8

    // ---- fused cooperative prep: CSR counting sort + converts (1 dispatch)
    CvtDesc cd;
    cd.s[0] = Wl1; cd.d[0] = Wcat1T;           cd.K[0] = 128; cd.N[0] = 256; cd.KD[0] = 256; cd.KO[0] = 0;
    cd.s[1] = Wr1; cd.d[1] = Wcat1T;           cd.K[1] = 128; cd.N[1] = 256; cd.KD[1] = 256; cd.KO[1] = 128;
    cd.s[2] = Wl2; cd.d[2] = Wcat2T;           cd.K[2] = 256; cd.N[2] = 128; cd.KD[2] = 256; cd.KO[2] = 0;
    cd.s[3] = Wr2; cd.d[3] = Wcat2T + 128*256; cd.K[3] = 256; cd.N[3] = 128; cd.KD[3] = 256; cd.KO[3] = 0;
    cd.s[4] = Wl3; cd.d[4] = Wcat3T;           cd.K[4] = 128; cd.N[4] = 64;  cd.KD[4] = 128; cd.KO[4] = 0;
    cd.s[5] = Wr3; cd.d[5] = Wcat3T + 64*128;  cd.K[5] = 128; cd.N[5] = 64;  cd.KD[5] = 128; cd.KO[5] = 0;

    int nchunk = (E + 4095) / 4096;           // 196
    int n4 = M * 128 / 4;                     // 1.6M float4
    int xunits = (n4 + 255) / 256;            // 6250
    int tunits = xunits + 6 * 128;            // + 768 weight units

    {
        const float* xa = x; const int* sa = src; const int* da = dst;
        int Ma = M, Ea = E, Pa = P;
        void* args[] = { (void*)&xa, (void*)&sa, (void*)&da,
                         (void*)&pcount, (void*)&pbase, (void*)&pcursor,
                         (void*)&pairs, (void*)&csr16, (void*)&deg,
                         (void*)&row_start, (void*)&cd, (void*)&AX, (void*)&x8,
                         (void*)&Ma, (void*)&Ea, (void*)&Pa, (void*)&nchunk,
                         (void*)&n4, (void*)&xunits, (void*)&tunits };
        hipLaunchCooperativeKernel((void*)k_prep, dim3(512), dim3(256),
                                   args, 0, stream);
    }

    const int gm64 = (M + 63) / 64;           // 782
    const int ga128 = (M + 7) / 8;            // 6250 (F=128: 8 nodes/block)
    const int ga64  = (M + 15) / 16;          // 3125 (F=64: 16 nodes/block)

    // ---- layer 1: aggx (AX cols 0..127) = agg(x8 fp8);
    //      h1 = relu(AX @ Wcat1T + b1)   [single K=256 GEMM]
    agg_bf<128, 0, 1, 128, 256><<<ga128, 256, 0, stream>>>(
        x8, csr16, row_start, deg, nullptr, nullptr, AX, M);
    mgemm<64, 64, 256, 1, 0><<<dim3(gm64, 4), 256, 0, stream>>>(
        AX, Wcat1T, b1, h1, 256, h1, 256, 256, M, 256);

    // ---- layer 2: [t2_8(fp8)|u2] = h1@Wcat2; h2 = relu(agg(t2_8) + u2 + b2)
    mgemm<64, 64, 256, 0, 1><<<dim3(gm64, 4), 256, 0, stream>>>(
        h1, Wcat2T, nullptr, t2_8, 128, u2, 128, 128, M, 256);
    agg_bf<128, 1, 1, 128, 128><<<ga128, 256, 0, stream>>>(
        t2_8, csr16, row_start, deg, u2, b2, h2, M);

    // ---- layer 3: [t3_8(fp8)|u3] = h2@Wcat3; out = sigmoid(agg(t3_8) + u3 + b3)
    mgemm<64, 64, 128, 0, 1><<<dim3(gm64, 2), 256, 0, stream>>>(
        h2, Wcat3T, nullptr, t3_8, 64, u3, 64, 64, M, 128);
    agg_bf<64, 2, 1, 64, 64><<<ga64, 256, 0, stream>>>(
        t3_8, csr16, row_start, deg, u3, b3, (float*)d_out, M);
}

// Round 20
// 189.037 us; speedup vs baseline: 2.2577x; 2.2577x over previous
//
#include <hip/hip_runtime.h>
#include <cstddef>

// ---------------------------------------------------------------------------
// SAGEBlock: 3-layer GraphSAGE (mean aggr), N=50000, E=800000.
//   h1 = relu(agg(x)@Wl1 + x@Wr1 + b1)              128 -> 256
//   h2 = relu(agg(h1@Wl2) + h1@Wr2 + b2)            256 -> 128
//   out= sigmoid(agg(h2@Wl3) + h2@Wr3 + b3)         128 -> 64
// R20: revert to R18 (189.6us best). R19's cooperative fused prep regressed
//     2.3x: grid.sync() at 512 blocks is a device-wide spin barrier and the
//     heterogeneous phases (196-block CSR vs idle rest) made every sync cost
//     the straggler max (~250us spin). Lesson: coop grid phases need full-grid
//     balanced work. Config: fp8 gathers (x8/t2_8/t3_8), pipelined dbuf GEMM
//     (gload_lds + pre-swizzled source), layer-1 K=256 fusion, F/4-lane agg,
//     LDS counting-sort CSR, merged cvt dispatch.
// ---------------------------------------------------------------------------

using frag  = __attribute__((ext_vector_type(8))) short;   // 8 bf16
using f32x4 = __attribute__((ext_vector_type(4))) float;
using vf2   = __attribute__((ext_vector_type(2))) float;
typedef unsigned char u8;

constexpr int PBITS = 9;                 // 512 nodes per partition
constexpr int PSZ   = 1 << PBITS;
constexpr int PMAX  = 128;               // max partitions (M <= 65536)

__device__ __forceinline__ ushort f2bf(float f) {
    union { float f; unsigned u; } v; v.f = f;
    unsigned r = v.u + 0x7FFF + ((v.u >> 16) & 1);   // RNE
    return (ushort)(r >> 16);
}
__device__ __forceinline__ float bf2f(ushort u) {
    union { unsigned u; float f; } v; v.u = ((unsigned)u) << 16;
    return v.f;
}

// ---------------- CSR build: counting sort by partition ----------------

__global__ __launch_bounds__(256)
void k_pcount(const int* __restrict__ dst, int* __restrict__ pcount, int E, int P) {
    __shared__ int h[PMAX];
    int t = threadIdx.x;
    if (t < P) h[t] = 0;
    __syncthreads();
    int base = blockIdx.x * 4096;
    int n = min(4096, E - base);
    for (int i = t; i < n; i += 256)
        atomicAdd(&h[dst[base + i] >> PBITS], 1);
    __syncthreads();
    if (t < P && h[t]) atomicAdd(&pcount[t], h[t]);
}

__global__ void k_pscan(const int* __restrict__ pcount, int* __restrict__ pbase,
                        int* __restrict__ pcursor, int P) {
    if (threadIdx.x == 0) {
        int run = 0;
        for (int p = 0; p < P; ++p) { pbase[p] = run; pcursor[p] = run; run += pcount[p]; }
        pbase[P] = run;
    }
}

__global__ __launch_bounds__(256)
void k_scatter(const int* __restrict__ src, const int* __restrict__ dst,
               int* __restrict__ pcursor, unsigned* __restrict__ pairs, int E, int P) {
    __shared__ int h[PMAX];
    __shared__ int off[PMAX];
    int t = threadIdx.x;
    if (t < P) h[t] = 0;
    __syncthreads();
    int base = blockIdx.x * 4096;
    int pp[16]; int pr[16]; unsigned pk[16];
    #pragma unroll
    for (int ii = 0; ii < 16; ++ii) {          // static index -> stays in VGPRs
        int idx = base + ii * 256 + t;
        bool v = idx < E;
        int d = v ? dst[idx] : 0;
        int p = d >> PBITS;
        pp[ii] = v ? p : -1;
        pr[ii] = v ? atomicAdd(&h[p], 1) : 0;
        pk[ii] = v ? ((unsigned)src[idx] | ((unsigned)(d & (PSZ - 1)) << 16)) : 0u;
    }
    __syncthreads();
    if (t < P && h[t]) off[t] = atomicAdd(&pcursor[t], h[t]);
    __syncthreads();
    #pragma unroll
    for (int ii = 0; ii < 16; ++ii)
        if (pp[ii] >= 0) pairs[off[pp[ii]] + pr[ii]] = pk[ii];
}

__global__ __launch_bounds__(256)
void k_build(const unsigned* __restrict__ pairs, const int* __restrict__ pbase,
             int* __restrict__ deg, int* __restrict__ row_start,
             ushort* __restrict__ csr16, int M) {
    __shared__ int cnt[PSZ];
    __shared__ int ls[PSZ];
    __shared__ int fil[PSZ];
    __shared__ int ws[256];
    int pid = blockIdx.x;
    int t = threadIdx.x;
    int n0 = pid << PBITS;
    int L = min(PSZ, M - n0);
    int wb = pbase[pid], we = pbase[pid + 1];
    int ne = we - wb;
    for (int j = t; j < PSZ; j += 256) { cnt[j] = 0; fil[j] = 0; }
    __syncthreads();
    for (int i = t; i < ne; i += 256)
        atomicAdd(&cnt[pairs[wb + i] >> 16], 1);
    __syncthreads();
    int a = cnt[2 * t], b = cnt[2 * t + 1];
    ws[t] = a + b;
    __syncthreads();
    for (int o = 1; o < 256; o <<= 1) {
        int v = (t >= o) ? ws[t - o] : 0;
        __syncthreads();
        ws[t] += v;
        __syncthreads();
    }
    int excl = (t > 0) ? ws[t - 1] : 0;
    ls[2 * t] = excl; ls[2 * t + 1] = excl + a;
    __syncthreads();
    for (int j = t; j < L; j += 256) {
        deg[n0 + j] = cnt[j];
        row_start[n0 + j] = wb + ls[j];
    }
    for (int i = t; i < ne; i += 256) {
        unsigned pk = pairs[wb + i];
        int ln = pk >> 16;
        int pos = wb + ls[ln] + atomicAdd(&fil[ln], 1);
        csr16[pos] = (ushort)(pk & 0xFFFFu);
    }
}

// ---------------- dtype converts (single dispatch) ----------------

struct CvtDesc {
    const float* s[6];
    ushort*      d[6];
    int K[6];    // src K
    int N[6];    // src N
    int KD[6];   // dst row stride
    int KO[6];   // dst k offset
};

// blocks [0, xblocks): x -> AX bf16 cols 128..255 + x8 fp8
// blocks [xblocks, ...): 6 weight transposes (128 blocks each)
__global__ void k_cvt_all(CvtDesc c, const float* __restrict__ x,
                          ushort* __restrict__ AX, u8* __restrict__ x8,
                          int n4, int xblocks) {
    int bid = blockIdx.x;
    if (bid < xblocks) {
        int i = bid * 256 + threadIdx.x;
        if (i < n4) {
            int row = i >> 5;            // 32 float4 per row of 128
            int c4  = i & 31;
            float4 v = ((const float4*)x)[i];
            ushort4 o; o.x = f2bf(v.x); o.y = f2bf(v.y); o.z = f2bf(v.z); o.w = f2bf(v.w);
            *(ushort4*)(AX + (size_t)row * 256 + 128 + c4 * 4) = o;
            int pk = __builtin_amdgcn_cvt_pk_fp8_f32(v.x, v.y, 0, false);
            pk = __builtin_amdgcn_cvt_pk_fp8_f32(v.z, v.w, pk, true);
            *(int*)(x8 + (size_t)row * 128 + c4 * 4) = pk;
        }
    } else {
        int wb = bid - xblocks;
        int wi = wb >> 7;
        int t = (wb & 127) * 256 + threadIdx.x;
        int K = c.K[wi], N = c.N[wi];
        if (t < K * N) {
            int k = t / N, n = t % N;
            c.d[wi][(size_t)n * c.KD[wi] + c.KO[wi] + k] = f2bf(c.s[wi][t]);
        }
    }
}

// ---------------- mean aggregation + fused epilogue ----------------
// F/4 lanes per node. IN8: gather input is fp8 (LDI in BYTES, uint/lane);
// else bf16 (LDI in ushorts, ushort4/lane). LDO: out row stride.
// EPI: 0 = plain bf16 out; 1 = relu(agg+u+b) bf16 out; 2 = sigmoid(agg+u+b) f32 out

template <int F, int EPI, int IN8, int LDI, int LDO>
__global__ __launch_bounds__(256)
void agg_bf(const void* __restrict__ inv, const ushort* __restrict__ csr16,
            const int* __restrict__ row_start, const int* __restrict__ deg,
            const ushort* __restrict__ u, const float* __restrict__ bias,
            void* __restrict__ out, int nN) {
    constexpr int GPL = F / 4;                 // lanes per node
    constexpr int NPB = 256 / GPL;             // nodes per block
    int gid  = threadIdx.x / GPL;
    int li   = threadIdx.x % GPL;
    int node = blockIdx.x * NPB + gid;
    bool valid = node < nN;
    int start = valid ? row_start[node] : 0;
    int d     = valid ? deg[node] : 0;
    float a0 = 0.f, a1 = 0.f, a2 = 0.f, a3 = 0.f;

    auto gat = [&](int j) {
        int s = csr16[start + j];
        if constexpr (IN8) {
            int uu = *(const int*)((const u8*)inv + (size_t)s * LDI + li * 4);
            vf2 lo = __builtin_amdgcn_cvt_pk_f32_fp8(uu, false);
            vf2 hi = __builtin_amdgcn_cvt_pk_f32_fp8(uu, true);
            a0 += lo[0]; a1 += lo[1]; a2 += hi[0]; a3 += hi[1];
        } else {
            ushort4 uv = *(const ushort4*)((const ushort*)inv + (size_t)s * LDI + li * 4);
            a0 += bf2f(uv.x); a1 += bf2f(uv.y); a2 += bf2f(uv.z); a3 += bf2f(uv.w);
        }
    };

    int j = 0;
    for (; j + 8 <= d; j += 8) {
        gat(j); gat(j+1); gat(j+2); gat(j+3);
        gat(j+4); gat(j+5); gat(j+6); gat(j+7);
    }
    for (; j + 2 <= d; j += 2) { gat(j); gat(j+1); }
    for (; j < d; ++j) gat(j);

    if (!valid) return;
    float inv_d = 1.f / (float)(d > 0 ? d : 1);
    a0 *= inv_d; a1 *= inv_d; a2 *= inv_d; a3 *= inv_d;

    size_t o4 = (size_t)node * LDO + li * 4;
    if constexpr (EPI == 0) {
        ushort4 o; o.x = f2bf(a0); o.y = f2bf(a1); o.z = f2bf(a2); o.w = f2bf(a3);
        *(ushort4*)((ushort*)out + o4) = o;
    } else {
        ushort4 uv = *(const ushort4*)(u + (size_t)node * F + li * 4);
        float4 bv = *(const float4*)(bias + li * 4);
        a0 += bf2f(uv.x) + bv.x;
        a1 += bf2f(uv.y) + bv.y;
        a2 += bf2f(uv.z) + bv.z;
        a3 += bf2f(uv.w) + bv.w;
        if constexpr (EPI == 1) {
            ushort4 o;
            o.x = f2bf(fmaxf(a0, 0.f)); o.y = f2bf(fmaxf(a1, 0.f));
            o.z = f2bf(fmaxf(a2, 0.f)); o.w = f2bf(fmaxf(a3, 0.f));
            *(ushort4*)((ushort*)out + o4) = o;
        } else {
            float4 o;
            o.x = 1.f / (1.f + __expf(-a0)); o.y = 1.f / (1.f + __expf(-a1));
            o.z = 1.f / (1.f + __expf(-a2)); o.w = 1.f / (1.f + __expf(-a3));
            *(float4*)((float*)out + o4) = o;
        }
    }
}

// ---------------- bf16 MFMA GEMM: 2-phase pipelined, gload_lds staging ------
// C[M,N] = act( A@B^T (+ bias) ); col < nsplit -> C1, else C2.
// OUT8: C1 stored as fp8 (gather operand); C2 always bf16.
// Double-buffered LDS, ONE barrier per K-step; prefetch overlaps compute.
// Swizzle: linear LDS dest + inverse-XOR global source (rule #21).

__device__ __forceinline__ void gload16(const ushort* gp, char* lp) {
    __builtin_amdgcn_global_load_lds(
        (const __attribute__((address_space(1))) void*)gp,
        (__attribute__((address_space(3))) void*)lp, 16, 0, 0);
}

template <int BM, int BN, int K, int ACT, int OUT8>
__global__ __launch_bounds__(256)
void mgemm(const ushort* __restrict__ A, const ushort* __restrict__ B,
           const float* __restrict__ bias,
           void* __restrict__ C1, int ld1,
           ushort* __restrict__ C2, int ld2, int nsplit,
           int M, int N) {
    constexpr int NW = 4;                     // waves per block
    constexpr int WM = 2, WN = 2;
    constexpr int MF = BM / (WM * 16);
    constexpr int NF = BN / (WN * 16);
    constexpr int NSTEP = K / 64;
    constexpr int TB = (BM + BN) * 128;       // bytes per buffer
    __shared__ char lds[2 * TB];

    const int tid  = threadIdx.x;
    const int lane = tid & 63;
    const int wid  = tid >> 6;
    const int wm   = wid % WM, wn = wid / WM;
    const int bm   = blockIdx.x * BM;
    const int bn   = blockIdx.y * BN;
    const int l15  = lane & 15;
    const int lhi  = lane >> 4;
    const int lr8  = lane >> 3;               // row within 8-row gload group
    const int lf   = lane & 7;                // frag slot within row

    auto stage = [&](int buf, int k0) {
        char* As = lds + buf * TB;
        char* Bs = As + BM * 128;
        #pragma unroll
        for (int it = 0; it < BM / (8 * NW); ++it) {
            int r0 = (it * NW + wid) * 8;
            int row = r0 + lr8;
            int gr = bm + row; if (gr >= M) gr = M - 1;   // clamp; junk rows unused
            int gfc = lf ^ (row & 7);
            gload16(A + (size_t)gr * K + k0 + gfc * 8, As + r0 * 128);
        }
        #pragma unroll
        for (int it = 0; it < BN / (8 * NW); ++it) {
            int r0 = (it * NW + wid) * 8;
            int row = r0 + lr8;
            int gfc = lf ^ (row & 7);
            gload16(B + (size_t)(bn + row) * K + k0 + gfc * 8, Bs + r0 * 128);
        }
    };

    f32x4 acc[MF][NF] = {};

    stage(0, 0);
    #pragma unroll
    for (int s = 0; s < NSTEP; ++s) {
        __syncthreads();                       // drains stage(s)
        if (s + 1 < NSTEP) stage((s + 1) & 1, (s + 1) * 64);   // prefetch overlaps compute
        char* As = lds + (s & 1) * TB;
        char* Bs = As + BM * 128;
        #pragma unroll
        for (int ks = 0; ks < 2; ++ks) {
            const int kb = ks * 64 + lhi * 16;
            frag a[MF], b[NF];
            #pragma unroll
            for (int mf = 0; mf < MF; ++mf) {
                int row = wm * MF * 16 + mf * 16 + l15;
                a[mf] = *(const frag*)(As + row * 128 + (kb ^ ((row & 7) << 4)));
            }
            #pragma unroll
            for (int nf = 0; nf < NF; ++nf) {
                int row = wn * NF * 16 + nf * 16 + l15;
                b[nf] = *(const frag*)(Bs + row * 128 + (kb ^ ((row & 7) << 4)));
            }
            #pragma unroll
            for (int mf = 0; mf < MF; ++mf)
                #pragma unroll
                for (int nf = 0; nf < NF; ++nf)
                    acc[mf][nf] = __builtin_amdgcn_mfma_f32_16x16x32_bf16(
                        a[mf], b[nf], acc[mf][nf], 0, 0, 0);
        }
    }

    #pragma unroll
    for (int mf = 0; mf < MF; ++mf) {
        #pragma unroll
        for (int r = 0; r < 4; ++r) {
            int gm = bm + wm * MF * 16 + mf * 16 + lhi * 4 + r;
            if (gm >= M) continue;
            #pragma unroll
            for (int nf = 0; nf < NF; ++nf) {
                int gn = bn + wn * NF * 16 + nf * 16 + l15;
                float v = acc[mf][nf][r];
                if (bias) v += bias[gn];
                if (ACT == 1) v = fmaxf(v, 0.f);
                if (gn < nsplit) {
                    if constexpr (OUT8) {
                        int pk = __builtin_amdgcn_cvt_pk_fp8_f32(v, v, 0, false);
                        ((u8*)C1)[(size_t)gm * ld1 + gn] = (u8)(pk & 0xFF);
                    } else {
                        ((ushort*)C1)[(size_t)gm * ld1 + gn] = f2bf(v);
                    }
                } else {
                    C2[(size_t)gm * ld2 + (gn - nsplit)] = f2bf(v);
                }
            }
        }
    }
}

// ---------------------------------------------------------------------------

extern "C" void kernel_launch(void* const* d_in, const int* in_sizes, int n_in,
                              void* d_out, int out_size, void* d_ws, size_t ws_size,
                              hipStream_t stream) {
    const float* x   = (const float*)d_in[0];
    const int*   ei  = (const int*)d_in[1];
    const float* Wl1 = (const float*)d_in[2];
    const float* Wr1 = (const float*)d_in[3];
    const float* b1  = (const float*)d_in[4];
    const float* Wl2 = (const float*)d_in[5];
    const float* Wr2 = (const float*)d_in[6];
    const float* b2  = (const float*)d_in[7];
    const float* Wl3 = (const float*)d_in[8];
    const float* Wr3 = (const float*)d_in[9];
    const float* b3  = (const float*)d_in[10];

    const int M = in_sizes[0] / 128;   // 50000
    const int E = in_sizes[1] / 2;     // 800000
    const int P = (M + PSZ - 1) / PSZ; // 98 partitions
    const int* src = ei;
    const int* dst = ei + E;

    char* w = (char*)d_ws;
    auto alloc = [&](size_t bytes) -> void* {
        void* p = (void*)w;
        w += (bytes + 255) & ~(size_t)255;
        return p;
    };
    int* pcount    = (int*)alloc((size_t)PMAX * 4);
    int* pbase     = (int*)alloc((size_t)(PMAX + 1) * 4);
    int* pcursor   = (int*)alloc((size_t)PMAX * 4);
    unsigned* pairs = (unsigned*)alloc((size_t)E * 4);
    ushort* csr16  = (ushort*)alloc((size_t)E * 2);
    int* deg       = (int*)alloc((size_t)M * 4);
    int* row_start = (int*)alloc((size_t)M * 4);
    ushort* Wcat1T = (ushort*)alloc(256 * 256 * 2);       // [256 n][256 k]: Wl1|Wr1 (K-concat)
    ushort* Wcat2T = (ushort*)alloc(256 * 256 * 2);       // [256 n][256 k]: Wl2|Wr2 (N-concat)
    ushort* Wcat3T = (ushort*)alloc(128 * 128 * 2);       // [128 n][128 k]: Wl3|Wr3 (N-concat)
    ushort* AX   = (ushort*)alloc((size_t)M * 256 * 2);   // [aggx | x_bf] interleaved
    ushort* bufB = (ushort*)alloc((size_t)M * 128 * 2);   // h2
    ushort* bufH = (ushort*)alloc((size_t)M * 256 * 2);   // h1
    ushort* bufC = (ushort*)alloc((size_t)M * 128 * 2);   // u2 -> u3
    u8* fp8buf   = (u8*)alloc((size_t)M * 128);           // x8 -> t2_8 -> t3_8 (time-shared)
    (void)ws_size; (void)n_in; (void)out_size;

    ushort* h2 = bufB;
    ushort* h1 = bufH;
    ushort* u2 = bufC;   ushort* u3 = bufC;
    u8* x8   = fp8buf;   u8* t2_8 = fp8buf;   u8* t3_8 = fp8buf;
    // x8 dead before gemm2 writes t2_8; t2_8 dead (agg2 done) before gemm3 writes t3_8

    // CSR build: only pcount needs zeroing (<=512B)
    hipMemsetAsync(pcount, 0, (size_t)PMAX * 4, stream);
    const int nchunk = (E + 4095) / 4096;     // 196
    k_pcount<<<nchunk, 256, 0, stream>>>(dst, pcount, E, P);
    k_pscan<<<1, 64, 0, stream>>>(pcount, pbase, pcursor, P);
    k_scatter<<<nchunk, 256, 0, stream>>>(src, dst, pcursor, pairs, E, P);
    k_build<<<P, 256, 0, stream>>>(pairs, pbase, deg, row_start, csr16, M);

    // converts (single dispatch: x + 6 weights)
    CvtDesc cd;
    cd.s[0] = Wl1; cd.d[0] = Wcat1T;           cd.K[0] = 128; cd.N[0] = 256; cd.KD[0] = 256; cd.KO[0] = 0;
    cd.s[1] = Wr1; cd.d[1] = Wcat1T;           cd.K[1] = 128; cd.N[1] = 256; cd.KD[1] = 256; cd.KO[1] = 128;
    cd.s[2] = Wl2; cd.d[2] = Wcat2T;           cd.K[2] = 256; cd.N[2] = 128; cd.KD[2] = 256; cd.KO[2] = 0;
    cd.s[3] = Wr2; cd.d[3] = Wcat2T + 128*256; cd.K[3] = 256; cd.N[3] = 128; cd.KD[3] = 256; cd.KO[3] = 0;
    cd.s[4] = Wl3; cd.d[4] = Wcat3T;           cd.K[4] = 128; cd.N[4] = 64;  cd.KD[4] = 128; cd.KO[4] = 0;
    cd.s[5] = Wr3; cd.d[5] = Wcat3T + 64*128;  cd.K[5] = 128; cd.N[5] = 64;  cd.KD[5] = 128; cd.KO[5] = 0;
    const int n4 = M * 128 / 4;
    const int xblocks = (n4 + 255) / 256;     // 6250
    k_cvt_all<<<xblocks + 6 * 128, 256, 0, stream>>>(cd, x, AX, x8, n4, xblocks);

    const int gm64 = (M + 63) / 64;           // 782
    const int ga128 = (M + 7) / 8;            // 6250 (F=128: 8 nodes/block)
    const int ga64  = (M + 15) / 16;          // 3125 (F=64: 16 nodes/block)

    // ---- layer 1: aggx (AX cols 0..127) = agg(x8 fp8);
    //      h1 = relu(AX @ Wcat1T + b1)   [single K=256 GEMM]
    agg_bf<128, 0, 1, 128, 256><<<ga128, 256, 0, stream>>>(
        x8, csr16, row_start, deg, nullptr, nullptr, AX, M);
    mgemm<64, 64, 256, 1, 0><<<dim3(gm64, 4), 256, 0, stream>>>(
        AX, Wcat1T, b1, h1, 256, h1, 256, 256, M, 256);

    // ---- layer 2: [t2_8(fp8)|u2] = h1@Wcat2; h2 = relu(agg(t2_8) + u2 + b2)
    mgemm<64, 64, 256, 0, 1><<<dim3(gm64, 4), 256, 0, stream>>>(
        h1, Wcat2T, nullptr, t2_8, 128, u2, 128, 128, M, 256);
    agg_bf<128, 1, 1, 128, 128><<<ga128, 256, 0, stream>>>(
        t2_8, csr16, row_start, deg, u2, b2, h2, M);

    // ---- layer 3: [t3_8(fp8)|u3] = h2@Wcat3; out = sigmoid(agg(t3_8) + u3 + b3)
    mgemm<64, 64, 128, 0, 1><<<dim3(gm64, 2), 256, 0, stream>>>(
        h2, Wcat3T, nullptr, t3_8, 64, u3, 64, 64, M, 128);
    agg_bf<64, 2, 1, 64, 64><<<ga64, 256, 0, stream>>>(
        t3_8, csr16, row_start, deg, u3, b3, (float*)d_out, M);
}